// Round 10
// baseline (689.530 us; speedup 1.0000x reference)
//
#include <hip/hip_runtime.h>

// BNN conv3d forward: x (8,32,16,160,160) f32, w (32,32,1,3,3) f32
// out[n,o,d,h,w] = sum_i sum_{kh,kw} x[n,i,d,h+kh-1,w+kw-1] * we[o,i,kh,kw]
// we = (mean|w| over taps) * sign(w).  Implicit GEMM, mfma_f32_16x16x32_f16.
//
// Round-10: BARRIER-FREE direct-from-global conv. Rounds 4-9 proved
// source-level prefetch-across-barrier doesn't survive this compiler
// (VGPR counts showed in-flight regs never held). The fill kernel's 6.9 TB/s
// comes from pure TLP with no phases -- replicate that: no x-LDS, no main-
// loop barriers. Wave owns 2 output rows x 160 w; per 16-w strip x 4 input
// rows it loads 3(kw) x 8(ch) dwords straight from global (16-lane 64B
// segments; L1 absorbs the 3x kw overlap), cvt->f16, MFMA vs weight
// fragments in an 18KB LDS table (R1-verified layout). Row halo (2x logical)
// absorbed by L2 via XCD-chunked remap of 8-row blocks.

typedef _Float16 half8 __attribute__((ext_vector_type(8)));
typedef float    floatx4 __attribute__((ext_vector_type(4)));

#define DHW  409600   // 16*160*160 (channel stride)
#define HW   25600    // 160*160   (d stride)

__global__ __launch_bounds__(256, 4) void bnn_conv3d_direct(
        const float* __restrict__ x, const float* __restrict__ w,
        float* __restrict__ out) {
    // weight fragment table: [t:9][oh:2][lane:64][j:8] f16 = 18432 B
    __shared__ __align__(16) _Float16 wlds[9216];

    const int tid  = threadIdx.x;
    const int lane = tid & 63;
    const int wid  = tid >> 6;         // 0..3

    // ---- phase 0 (once): effective weights -> LDS fragment table ----------
    // wlds[((t*2+p)*64 + l)*8 + j] = we[o=p*16+(l&15)][i=(l>>4)*8+j][t]
    #pragma unroll
    for (int p4 = 0; p4 < 4; ++p4) {
        const int oi = tid * 4 + p4;       // o*32 + i
        const int o  = oi >> 5;
        const int i  = oi & 31;
        const float* wp = w + oi * 9;
        float s = 0.f;
        #pragma unroll
        for (int t = 0; t < 9; ++t) s += fabsf(wp[t]);
        s *= (1.f / 9.f);
        const int l = ((i >> 3) << 4) | (o & 15);
        const int p = o >> 4;
        const int j = i & 7;
        #pragma unroll
        for (int t = 0; t < 9; ++t) {
            const float v  = wp[t];
            const float sg = (v > 0.f) ? 1.f : ((v < 0.f) ? -1.f : 0.f);
            wlds[((t * 2 + p) * 64 + l) * 8 + j] = (_Float16)(s * sg);
        }
    }
    __syncthreads();   // the ONLY barrier in the kernel

    // ---- work mapping: 2560 blocks = 8n * 16d * 20 h-chunks of 8 rows -----
    // XCD-chunked remap: consecutive work ids (adjacent h-chunks) -> same XCD.
    const int bid = blockIdx.x;
    const int wk  = (bid & 7) * 320 + (bid >> 3);   // bijective, 2560 = 8*320
    const int hc  = wk % 20;
    const int nd  = wk / 20;
    const int d   = nd & 15;
    const int n   = nd >> 4;
    const int h0w = hc * 8 + wid * 2;  // this wave's first output row

    const int s16 = lane & 15;         // w-position within strip / out-ch
    const int kg  = lane >> 4;         // channel-group (A) / w-subgroup (D)

    const float* xb = x   + (n * 32 + kg * 8) * DHW + d * HW;  // +j*DHW+row*160+col
    float*       ob = out + (n * 32 + s16)    * DHW + d * HW;  // +oh*16*DHW+row*160

    const floatx4 z4 = {0.f, 0.f, 0.f, 0.f};

    // ---- main loop: 10 strips of 16 w; no barriers, pure TLP ---------------
    for (int gp = 0; gp < 10; ++gp) {
        const int gp16 = gp * 16;
        floatx4 acc[2][2] = {{z4, z4}, {z4, z4}};   // [row][oh], const-indexed

        #pragma unroll
        for (int rp = 0; rp < 4; ++rp) {           // input rows h0w-1 .. h0w+2
            const int  hr    = h0w - 1 + rp;
            const bool rowok = (0 <= hr) && (hr < 160);    // wave-uniform
            float v[3][8];
            if (rowok) {
                const float* xrow = xb + hr * 160;
                #pragma unroll
                for (int kw = 0; kw < 3; ++kw) {
                    const int col  = gp16 + s16 + kw - 1;
                    const int ccol = col < 0 ? 0 : (col > 159 ? 159 : col);
                    const float* pr = xrow + ccol;         // clamped addr
                    #pragma unroll
                    for (int j = 0; j < 8; ++j) v[kw][j] = pr[j * DHW];
                }
            } else {
                #pragma unroll
                for (int kw = 0; kw < 3; ++kw)
                    #pragma unroll
                    for (int j = 0; j < 8; ++j) v[kw][j] = 0.f;
            }
            // pack to A-fragments (zero the 2 edge lanes' OOB columns)
            half8 af[3];
            #pragma unroll
            for (int kw = 0; kw < 3; ++kw) {
                const int  col = gp16 + s16 + kw - 1;
                const bool ok  = rowok && (0 <= col) && (col < 160);
                #pragma unroll
                for (int j = 0; j < 8; ++j)
                    af[kw][j] = ok ? (_Float16)v[kw][j] : (_Float16)0.f;
            }
            // MFMA: input row rp feeds out-row0 (tap kh=rp) and out-row1 (kh=rp-1)
            #pragma unroll
            for (int kw = 0; kw < 3; ++kw) {
                if (rp < 3) {
                    const int t = rp * 3 + kw;
                    const half8 b0 = *reinterpret_cast<const half8*>(
                            &wlds[((t * 2 + 0) * 64 + lane) * 8]);
                    acc[0][0] = __builtin_amdgcn_mfma_f32_16x16x32_f16(af[kw], b0, acc[0][0], 0, 0, 0);
                    const half8 b1 = *reinterpret_cast<const half8*>(
                            &wlds[((t * 2 + 1) * 64 + lane) * 8]);
                    acc[0][1] = __builtin_amdgcn_mfma_f32_16x16x32_f16(af[kw], b1, acc[0][1], 0, 0, 0);
                }
                if (rp >= 1) {
                    const int t = (rp - 1) * 3 + kw;
                    const half8 c0 = *reinterpret_cast<const half8*>(
                            &wlds[((t * 2 + 0) * 64 + lane) * 8]);
                    acc[1][0] = __builtin_amdgcn_mfma_f32_16x16x32_f16(af[kw], c0, acc[1][0], 0, 0, 0);
                    const half8 c1 = *reinterpret_cast<const half8*>(
                            &wlds[((t * 2 + 1) * 64 + lane) * 8]);
                    acc[1][1] = __builtin_amdgcn_mfma_f32_16x16x32_f16(af[kw], c1, acc[1][1], 0, 0, 0);
                }
            }
        }

        // stores: 64B segments per o, same write-exact pattern as R5
        #pragma unroll
        for (int row = 0; row < 2; ++row)
            #pragma unroll
            for (int oh = 0; oh < 2; ++oh)
                *reinterpret_cast<floatx4*>(
                    ob + oh * 16 * DHW + (h0w + row) * 160 + gp16 + kg * 4)
                    = acc[row][oh];
    }
}

extern "C" void kernel_launch(void* const* d_in, const int* in_sizes, int n_in,
                              void* d_out, int out_size, void* d_ws, size_t ws_size,
                              hipStream_t stream) {
    const float* x = (const float*)d_in[0];
    const float* w = (const float*)d_in[1];
    float* out = (float*)d_out;
    // grid: 8 n * 16 d * 20 h-chunks (8 rows each; 4 waves x 2 rows)
    bnn_conv3d_direct<<<dim3(2560), dim3(256), 0, stream>>>(x, w, out);
}

// Round 11
// 283.121 us; speedup vs baseline: 2.4355x; 2.4355x over previous
//
#include <hip/hip_runtime.h>

// BNN conv3d forward: x (8,32,16,160,160) f32, w (32,32,1,3,3) f32
// out[n,o,d,h,w] = sum_i sum_{kh,kw} x[n,i,d,h+kh-1,w+kw-1] * we[o,i,kh,kw]
// we = (mean|w| over taps) * sign(w).  Implicit GEMM, mfma_f32_16x16x32_f16.
//
// Round-11: fine-grained row ring + 3 blocks/CU. Keeps the proven R1/R3/R5
// traffic geometry (TH=4 output rows x full 160 w, 5120 blocks, LDS-staged
// f16 tile, end-of-tile 128B-line stores) but restructures execution:
//  - LDS = 5-slot ring of single input rows (5 x 162 x 32 f16 = 50.6 KB)
//    -> 3 blocks/CU (vs 2 for all prior 62 KB variants).
//  - per barrier interval: ISSUE(row t+2) -> COMPUTE(row t) -> PACK(t+2),
//    natural program order: the vmcnt wait sits in PACK, AFTER ~36 MFMA +
//    18 ds_reads of COMPUTE, so HBM latency hides without any cross-barrier
//    register tricks (which rounds 4-9 proved the compiler defeats).
//  - load issue is spread uniformly over the block's lifetime -> per-CU
//    outstanding-read duty stays high (Little's law fix).
// Slot algebra: slot(r) = (r+1)%5. C(t) reads slots {t,t+1,t+2}%5,
// PACK(t+2) writes slot {t+3}%5 -> disjoint; reuse is 2 barriers apart.

typedef _Float16 half8  __attribute__((ext_vector_type(8)));
typedef _Float16 half4  __attribute__((ext_vector_type(4)));
typedef float    floatx4 __attribute__((ext_vector_type(4)));

#define DHW   409600   // 16*160*160 (channel stride)
#define HW    25600    // 160*160   (d stride)
#define SLOTH 5184     // halfs per ring slot = 162*32

__device__ __forceinline__ int w1swz(int w1) { return w1 ^ ((w1 >> 2) & 1); }
__device__ __forceinline__ int f2(int w1)    { return ((w1 >> 1) ^ (w1 >> 3)) & 3; }

__device__ __forceinline__ void barrier_raw() {
    // LDS-visibility barrier that does NOT drain vmcnt
    __builtin_amdgcn_sched_barrier(0);
    asm volatile("s_waitcnt lgkmcnt(0)" ::: "memory");
    __builtin_amdgcn_s_barrier();
    __builtin_amdgcn_sched_barrier(0);
}

// ---- kernel 1: effective-weight fragments -> ws (18 KB) -------------------
// ws[((t*2+p)*64 + l)*8 + j] = we[o=p*16+(l&15)][i=(l>>4)*8+j][t]
__global__ void bnn_wprep_kernel(const float* __restrict__ w,
                                 _Float16* __restrict__ ws) {
    const int tid = threadIdx.x;
    #pragma unroll
    for (int p4 = 0; p4 < 4; ++p4) {
        const int oi = tid * 4 + p4;
        const int o  = oi >> 5;
        const int i  = oi & 31;
        const float* wp = w + oi * 9;
        float s = 0.f;
        #pragma unroll
        for (int t = 0; t < 9; ++t) s += fabsf(wp[t]);
        s *= (1.f / 9.f);
        const int l = ((i >> 3) << 4) | (o & 15);
        const int p = o >> 4;
        const int j = i & 7;
        #pragma unroll
        for (int t = 0; t < 9; ++t) {
            const float v  = wp[t];
            const float sg = (v > 0.f) ? 1.f : ((v < 0.f) ? -1.f : 0.f);
            ws[((t * 2 + p) * 64 + l) * 8 + j] = (_Float16)(s * sg);
        }
    }
}

// ---- kernel 2: the conv ---------------------------------------------------
__global__ __launch_bounds__(320, 4) void bnn_conv3d_rr(
        const float* __restrict__ x, const _Float16* __restrict__ ws,
        float* __restrict__ out) {
    __shared__ __align__(16) _Float16 ldsh[5 * SLOTH];   // 51840 B

    const int tid  = threadIdx.x;
    const int lane = tid & 63;
    const int wv   = tid >> 6;          // wave 0..4

    // XCD-chunked remap: consecutive wk (adjacent ht, same n,d) -> same XCD
    const int bid = blockIdx.x;          // 5120 = 8 * 640
    const int wk  = (bid & 7) * 640 + (bid >> 3);
    const int ht  = wk % 40;
    const int nd  = wk / 40;
    const int d   = nd & 15;
    const int n   = nd >> 4;
    const int h0  = ht * 4;             // output rows h0..h0+3

    // ---- staging coords: item = (kq: ch-quad 0..7, wq: w-quad 0..39) ------
    const int wq = tid % 40;
    const int kq = tid / 40;
    const float* xb = x + (n * 32 + kq * 4) * DHW + d * HW + wq * 4;

    // ---- compute coords: wave owns wtiles {2wv, 2wv+1} --------------------
    const int s16 = lane & 15;
    const int kgr = lane >> 4;
    int rdo[2][3];
    #pragma unroll
    for (int gi = 0; gi < 2; ++gi)
        #pragma unroll
        for (int kw = 0; kw < 3; ++kw) {
            const int w1 = (2 * wv + gi) * 16 + s16 + kw;
            rdo[gi][kw]  = w1swz(w1) * 32 + ((kgr ^ f2(w1)) * 8);
        }
    float* ob = out + (n * 32 + s16) * DHW + d * HW + kgr * 4;

    floatx4 Ra[4], Rb[4], Rc[4];

    // ISSUE: 4 unconditional float4 loads for input row hr (clamped addr;
    // zeroing deferred to PACK, so no cndmask touches the load result).
    auto ISSUE = [&](int hr, floatx4* R) {
        const int hrc = hr < 0 ? 0 : (hr > 159 ? 159 : hr);
        const float* p = xb + hrc * 160;
        #pragma unroll
        for (int c = 0; c < 4; ++c)
            R[c] = *reinterpret_cast<const floatx4*>(p + c * DHW);
    };
    // PACK row r (slot (r+1)%5, passed as literal); ok is block-uniform.
    auto PACK = [&](int slot, bool ok, floatx4* R) {
        const int base = slot * SLOTH + (kq & 1) * 4;
        if (ok) {
            #pragma unroll
            for (int u = 0; u < 4; ++u) {
                const int w1 = wq * 4 + 1 + u;
                half4 pk;
                #pragma unroll
                for (int c = 0; c < 4; ++c) pk[c] = (_Float16)R[c][u];
                *reinterpret_cast<half4*>(
                    &ldsh[base + w1swz(w1) * 32 + (((kq >> 1) ^ f2(w1)) * 8)]) = pk;
            }
        } else {
            const half4 zz = {};
            #pragma unroll
            for (int u = 0; u < 4; ++u) {
                const int w1 = wq * 4 + 1 + u;
                *reinterpret_cast<half4*>(
                    &ldsh[base + w1swz(w1) * 32 + (((kq >> 1) ^ f2(w1)) * 8)]) = zz;
            }
        }
    };

    // weight fragments from the prep table (L2-resident): 18 x half8 = 72 VGPR
    half8 wf0[9], wf1[9];

    auto COMPUTE = [&](int t) {        // output row h0 + t
        #pragma unroll
        for (int gi = 0; gi < 2; ++gi) {
            floatx4 a0 = {0.f, 0.f, 0.f, 0.f};
            floatx4 a1 = {0.f, 0.f, 0.f, 0.f};
            #pragma unroll
            for (int kh = 0; kh < 3; ++kh) {
                const int so = ((t + kh) % 5) * SLOTH;
                #pragma unroll
                for (int kw = 0; kw < 3; ++kw) {
                    const half8 a = *reinterpret_cast<const half8*>(
                            &ldsh[so + rdo[gi][kw]]);
                    const int tap = kh * 3 + kw;
                    a0 = __builtin_amdgcn_mfma_f32_16x16x32_f16(a, wf0[tap], a0, 0, 0, 0);
                    a1 = __builtin_amdgcn_mfma_f32_16x16x32_f16(a, wf1[tap], a1, 0, 0, 0);
                }
            }
            const int g = 2 * wv + gi;
            float* op = ob + (h0 + t) * 160 + g * 16;
            *reinterpret_cast<floatx4*>(op)            = a0;  // o 0..15
            *reinterpret_cast<floatx4*>(op + 16 * DHW) = a1;  // o 16..31
        }
    };

    // ---------------- prologue ---------------------------------------------
    ISSUE(h0 - 1, Ra);                 // row -1
    ISSUE(h0 + 0, Rb);                 // row 0
    ISSUE(h0 + 1, Rc);                 // row 1
    // zero halo columns w1 in {0,161} of all 5 slots (written once; slots
    // are reused but halo cells are never overwritten)
    if (tid < 160) {
        const int word = tid & 15;
        const int col  = (tid >> 4) & 1;
        const int slot = tid >> 5;
        const int w1   = col ? 161 : 0;          // both fixed points of w1swz
        reinterpret_cast<unsigned int*>(ldsh)[((slot * SLOTH + w1 * 32) >> 1) + word] = 0u;
    }
    PACK(0, ht > 0, Ra);               // row -1 -> slot 0
    PACK(1, true,   Rb);               // row  0 -> slot 1
    PACK(2, true,   Rc);               // row  1 -> slot 2
    {
        const half8* fb = reinterpret_cast<const half8*>(ws);
        #pragma unroll
        for (int t = 0; t < 9; ++t) {
            wf0[t] = fb[(t * 2 + 0) * 64 + lane];
            wf1[t] = fb[(t * 2 + 1) * 64 + lane];
        }
    }
    barrier_raw();

    // ---------------- steady state: issue -> compute -> pack ---------------
    ISSUE(h0 + 2, Ra);  COMPUTE(0);  PACK(3, true, Ra);  barrier_raw();
    ISSUE(h0 + 3, Rb);  COMPUTE(1);  PACK(4, true, Rb);  barrier_raw();
    ISSUE(h0 + 4, Rc);  COMPUTE(2);  PACK(0, ht < 39, Rc);  barrier_raw();
    COMPUTE(3);
}

extern "C" void kernel_launch(void* const* d_in, const int* in_sizes, int n_in,
                              void* d_out, int out_size, void* d_ws, size_t ws_size,
                              hipStream_t stream) {
    const float* x = (const float*)d_in[0];
    const float* w = (const float*)d_in[1];
    float* out = (float*)d_out;
    _Float16* ws = (_Float16*)d_ws;     // 9216 halfs = 18 KB scratch
    bnn_wprep_kernel<<<dim3(1), dim3(256), 0, stream>>>(w, ws);
    // grid: 8 n * 16 d * 40 h-tiles (4 rows x full 160 w per block)
    bnn_conv3d_rr<<<dim3(5120), dim3(320), 0, stream>>>(x, ws, out);
}

// Round 12
// 252.964 us; speedup vs baseline: 2.7258x; 1.1192x over previous
//
#include <hip/hip_runtime.h>

// BNN conv3d forward: x (8,32,16,160,160) f32, w (32,32,1,3,3) f32
// out[n,o,d,h,w] = sum_i sum_{kh,kw} x[n,i,d,h+kh-1,w+kw-1] * we[o,i,kh,kw]
// we = (mean|w| over taps) * sign(w).  Implicit GEMM, mfma_f32_16x16x32_f16.
//
// Round-12: BARRIER-FREE wave-private staging. Every barriered structure
// (R1-R11) pinned at ~3.4 TB/s: block-wide barriers lockstep all waves into
// the same phase -> ~50% read-duty. The only 6.9 TB/s structure measured on
// this chip (fillBuffer) is barrier-free pure TLP. So: each wave owns a
// 2-row x 32-w output strip and a PRIVATE 10KB LDS tile ([4][40][32] f16,
// R5-verified swizzle). No __syncthreads anywhere. 12 independent waves/CU.
// Store rule (explains every WRITE inflation this session): both 64-B halves
// of a 128-B line stored back-to-back by the same wave -> strip = exactly
// one line per (row, o-channel), written whole.
// Halo (2x h, 1.25x w logical) absorbed by L2/L3 via XCD-chunked remap
// (R7 measured 462MB actual on 840MB logical -> absorption works).

typedef _Float16 half8  __attribute__((ext_vector_type(8)));
typedef float    floatx4 __attribute__((ext_vector_type(4)));

#define DHW  409600   // 16*160*160 (channel stride)
#define HW   25600    // 160*160   (d stride)

__device__ __forceinline__ int f2(int w1)  { return ((w1 >> 1) ^ (w1 >> 3)) & 3; }
__device__ __forceinline__ int w1s(int w1) { return w1 ^ ((w1 >> 2) & 1); }

// ---- kernel 1: effective-weight fragments -> ws (18 KB) -------------------
// ws[((t*2+p)*64 + l)*8 + j] = we[o=p*16+(l&15)][i=(l>>4)*8+j][t]
__global__ void bnn_wprep_kernel(const float* __restrict__ w,
                                 _Float16* __restrict__ ws) {
    const int tid = threadIdx.x;
    #pragma unroll
    for (int p4 = 0; p4 < 4; ++p4) {
        const int oi = tid * 4 + p4;
        const int o  = oi >> 5;
        const int i  = oi & 31;
        const float* wp = w + oi * 9;
        float s = 0.f;
        #pragma unroll
        for (int t = 0; t < 9; ++t) s += fabsf(wp[t]);
        s *= (1.f / 9.f);
        const int l = ((i >> 3) << 4) | (o & 15);
        const int p = o >> 4;
        const int j = i & 7;
        #pragma unroll
        for (int t = 0; t < 9; ++t) {
            const float v  = wp[t];
            const float sg = (v > 0.f) ? 1.f : ((v < 0.f) ? -1.f : 0.f);
            ws[((t * 2 + p) * 64 + l) * 8 + j] = (_Float16)(s * sg);
        }
    }
}

// ---- kernel 2: the conv ---------------------------------------------------
__global__ __launch_bounds__(256, 3) void bnn_conv3d_wp(
        const float* __restrict__ x, const _Float16* __restrict__ ws,
        float* __restrict__ out) {
    // 4 waves x 5120 halfs (10240 B each) = 40960 B; NO cross-wave sharing.
    __shared__ __align__(16) _Float16 ldsh[4 * 5120];

    const int tid  = threadIdx.x;
    const int lane = tid & 63;
    const int wv   = tid >> 6;

    // wave-unit u: 51200 = 8n * 16d * 80 row-pairs * 5 w-strips.
    // XCD-chunked remap at block level: consecutive wk -> same XCD.
    const int bid = blockIdx.x;                    // 12800 = 8 * 1600
    const int wk  = (bid & 7) * 1600 + (bid >> 3);
    const int u   = wk * 4 + wv;
    const int sx  = u % 5;
    const int rp  = (u / 5) % 80;
    const int nd  = u / 400;
    const int d   = nd & 15;
    const int n   = nd >> 4;
    const int ws0 = sx * 32;          // strip covers out w in [ws0, ws0+32)
    const int h0  = rp * 2;           // out rows h0, h0+1

    _Float16* myl = &ldsh[wv * 5120]; // private tile [r:4][w1:40][ch:32] swz

    // ---- staging: 160 items = (r:4, kg:4, wq:10); lane gets items
    //      {lane, lane+64, lane+128(<160)}. Per item: 8 float4 (ch-octet).
    int   r_[3], kg_[3], w1b_[3];
    bool  ok_[3];
    const float* p_[3];
    #pragma unroll
    for (int i = 0; i < 3; ++i) {
        const int idx = i * 64 + lane;
        const int wq  = idx % 10;
        kg_[i] = (idx / 10) & 3;
        r_[i]  = idx / 40;
        const int col0 = ws0 - 4 + wq * 4;         // quad cols col0..col0+3
        const int h    = h0 - 1 + r_[i];
        const bool okr = (unsigned)h < 160u;
        const bool okc = (unsigned)col0 <= 156u;   // quad fully in-image
        ok_[i]  = okr && okc;
        const int hc = h < 0 ? 0 : (h > 159 ? 159 : h);
        const int cc = col0 < 0 ? 0 : (col0 > 156 ? 156 : col0);
        w1b_[i] = wq * 4;
        p_[i]   = x + (n * 32 + kg_[i] * 8) * DHW + d * HW + hc * 160 + cc;
    }

    floatx4 fl0[8], fl1[8], fl2[8];
    #pragma unroll
    for (int c = 0; c < 8; ++c) fl0[c] = *reinterpret_cast<const floatx4*>(p_[0] + c * DHW);
    #pragma unroll
    for (int c = 0; c < 8; ++c) fl1[c] = *reinterpret_cast<const floatx4*>(p_[1] + c * DHW);
    if (lane < 32) {
        #pragma unroll
        for (int c = 0; c < 8; ++c) fl2[c] = *reinterpret_cast<const floatx4*>(p_[2] + c * DHW);
    }
    __builtin_amdgcn_sched_barrier(0);   // pin all load issues before packs

    // ---- pack (zeros for OOB quads) ---------------------------------------
    #pragma unroll
    for (int uq = 0; uq < 4; ++uq) {
        const int w1 = w1b_[0] + uq;
        half8 pk;
        #pragma unroll
        for (int c = 0; c < 8; ++c) pk[c] = ok_[0] ? (_Float16)fl0[c][uq] : (_Float16)0.f;
        *reinterpret_cast<half8*>(&myl[r_[0] * 1280 + w1s(w1) * 32 + ((kg_[0] ^ f2(w1)) * 8)]) = pk;
    }
    #pragma unroll
    for (int uq = 0; uq < 4; ++uq) {
        const int w1 = w1b_[1] + uq;
        half8 pk;
        #pragma unroll
        for (int c = 0; c < 8; ++c) pk[c] = ok_[1] ? (_Float16)fl1[c][uq] : (_Float16)0.f;
        *reinterpret_cast<half8*>(&myl[r_[1] * 1280 + w1s(w1) * 32 + ((kg_[1] ^ f2(w1)) * 8)]) = pk;
    }
    if (lane < 32) {
        #pragma unroll
        for (int uq = 0; uq < 4; ++uq) {
            const int w1 = w1b_[2] + uq;
            half8 pk;
            #pragma unroll
            for (int c = 0; c < 8; ++c) pk[c] = ok_[2] ? (_Float16)fl2[c][uq] : (_Float16)0.f;
            *reinterpret_cast<half8*>(&myl[r_[2] * 1280 + w1s(w1) * 32 + ((kg_[2] ^ f2(w1)) * 8)]) = pk;
        }
    }

    // ---- weight fragments (L2-resident prep table) ------------------------
    half8 wf0[9], wf1[9];
    {
        const half8* fb = reinterpret_cast<const half8*>(ws);
        #pragma unroll
        for (int t = 0; t < 9; ++t) {
            wf0[t] = fb[(t * 2 + 0) * 64 + lane];
            wf1[t] = fb[(t * 2 + 1) * 64 + lane];
        }
    }

    // within-wave LDS visibility (no cross-wave sharing -> no s_barrier)
    __builtin_amdgcn_sched_barrier(0);
    asm volatile("s_waitcnt lgkmcnt(0)" ::: "memory");
    __builtin_amdgcn_sched_barrier(0);

    // ---- compute: A-frag lane l elem j = tile(r=rl+kh, w1=wt*16+(l&15)+kw+3,
    //      ch=(l>>4)*8+j);  D: w off = (l>>4)*4+reg, out ch = l&15 (+16*ot)
    const int s16 = lane & 15;
    const int kgr = lane >> 4;
    const floatx4 z4 = {0.f, 0.f, 0.f, 0.f};
    floatx4 acc[2][2][2];   // [rl][wt][ot] -- all indices compile-time
    #pragma unroll
    for (int rl = 0; rl < 2; ++rl)
        #pragma unroll
        for (int wt = 0; wt < 2; ++wt) { acc[rl][wt][0] = z4; acc[rl][wt][1] = z4; }

    #pragma unroll
    for (int kh = 0; kh < 3; ++kh) {
        #pragma unroll
        for (int kw = 0; kw < 3; ++kw) {
            const int tap = kh * 3 + kw;
            #pragma unroll
            for (int rl = 0; rl < 2; ++rl) {
                const int r = rl + kh;
                #pragma unroll
                for (int wt = 0; wt < 2; ++wt) {
                    const int w1 = wt * 16 + s16 + kw + 3;
                    const half8 a = *reinterpret_cast<const half8*>(
                        &myl[r * 1280 + w1s(w1) * 32 + ((kgr ^ f2(w1)) * 8)]);
                    acc[rl][wt][0] = __builtin_amdgcn_mfma_f32_16x16x32_f16(a, wf0[tap], acc[rl][wt][0], 0, 0, 0);
                    acc[rl][wt][1] = __builtin_amdgcn_mfma_f32_16x16x32_f16(a, wf1[tap], acc[rl][wt][1], 0, 0, 0);
                }
            }
        }
    }

    // ---- stores: per (rl, ot) the two wt halves back-to-back = one full
    //      128-B line (ws0 is 32-aligned -> line-aligned) -------------------
    #pragma unroll
    for (int rl = 0; rl < 2; ++rl) {
        #pragma unroll
        for (int ot = 0; ot < 2; ++ot) {
            float* op = out + (n * 32 + ot * 16 + s16) * DHW + d * HW
                            + (h0 + rl) * 160 + ws0 + kgr * 4;
            *reinterpret_cast<floatx4*>(op)      = acc[rl][0][ot];
            *reinterpret_cast<floatx4*>(op + 16) = acc[rl][1][ot];
        }
    }
}

extern "C" void kernel_launch(void* const* d_in, const int* in_sizes, int n_in,
                              void* d_out, int out_size, void* d_ws, size_t ws_size,
                              hipStream_t stream) {
    const float* x = (const float*)d_in[0];
    const float* w = (const float*)d_in[1];
    float* out = (float*)d_out;
    _Float16* ws = (_Float16*)d_ws;     // 9216 halfs = 18 KB scratch
    bnn_wprep_kernel<<<dim3(1), dim3(256), 0, stream>>>(w, ws);
    // grid: 12800 blocks x 4 independent waves = 51200 strip-units
    bnn_conv3d_wp<<<dim3(12800), dim3(256), 0, stream>>>(x, ws, out);
}

// Round 13
// 188.508 us; speedup vs baseline: 3.6578x; 1.3419x over previous
//
#include <hip/hip_runtime.h>
#include <stdint.h>

// BNN conv3d forward: x (8,32,16,160,160) f32, w (32,32,1,3,3) f32
// out = conv3d(x, we), we = (mean|w| over taps)*sign(w). kD=1 -> 2D conv.
// Implicit GEMM, mfma_f32_16x16x32_f16 (M=16 w-positions, N=16 out-ch, K=32 in-ch).
//
// Round-13: global_load_lds DMA pipeline (m97/m201 mechanism). Register
// prefetch is compiler-defeated (R4-R12); global_load_lds has NO register
// result -> nothing to shuffle/drain. Block (320thr, 1/CU) owns 40 output
// rows x full 160 w of one (n,d). Per row-unit (20KB f32):
//   DMA: 20x global_load_lds(16B) -> LDS scratch (3-slot ring, wave-aligned:
//        wave wv loads w in [32wv,32wv+32) for all 32 ch)
//   PACK: own-wave scratch -> f16 ring (4 slots, R5-verified swizzle)
//   COMPUTE: R5 fragment path, 36 MFMA/wave/row; write-exact stores.
// Steady state: 2 rows DMA (40KB) ALWAYS outstanding per CU (counted vmcnt,
// never 0; raw lgkm-only barriers). Schedule per iter t:
//   vmcnt(12); PACK(t+2); barrier; DMA(t+4); COMPUTE(t)

typedef _Float16 half8  __attribute__((ext_vector_type(8)));
typedef float    floatx4 __attribute__((ext_vector_type(4)));

#define DHW 409600          // channel stride (floats)
#define HW  25600           // d stride
#define RING_SLOT_B 10368   // 162 cells * 64 B
#define RING_B      41472   // 4 ring slots
#define SCR_SLOT_B  20480   // 160 w * 32 ch * 4 B
#define LDS_TOTAL   102912  // ring + 3 scratch slots

__device__ __forceinline__ int w1s(int w1) { return w1 ^ ((w1 >> 2) & 1); }
__device__ __forceinline__ int f2v(int w1) { return ((w1 >> 1) ^ (w1 >> 3)) & 3; }

typedef const __attribute__((address_space(1))) uint32_t* gas1;
typedef __attribute__((address_space(3))) uint32_t* las3;
__device__ __forceinline__ void gld16(const void* g, void* l) {
    __builtin_amdgcn_global_load_lds((gas1)g, (las3)l, 16, 0, 0);
}
#define VMCNT(N) do { asm volatile("s_waitcnt vmcnt(" #N ")" ::: "memory"); \
                      __builtin_amdgcn_sched_barrier(0); } while (0)
__device__ __forceinline__ void barrier_raw() {
    __builtin_amdgcn_sched_barrier(0);
    asm volatile("s_waitcnt lgkmcnt(0)" ::: "memory");
    __builtin_amdgcn_s_barrier();
    __builtin_amdgcn_sched_barrier(0);
}

// ---- kernel 1: effective-weight fragments -> ws (18 KB) -------------------
__global__ void bnn_wprep_kernel(const float* __restrict__ w,
                                 _Float16* __restrict__ ws) {
    const int tid = threadIdx.x;
    #pragma unroll
    for (int p4 = 0; p4 < 4; ++p4) {
        const int oi = tid * 4 + p4;
        const int o  = oi >> 5;
        const int i  = oi & 31;
        const float* wp = w + oi * 9;
        float s = 0.f;
        #pragma unroll
        for (int t = 0; t < 9; ++t) s += fabsf(wp[t]);
        s *= (1.f / 9.f);
        const int l = ((i >> 3) << 4) | (o & 15);
        const int p = o >> 4;
        const int j = i & 7;
        #pragma unroll
        for (int t = 0; t < 9; ++t) {
            const float v  = wp[t];
            const float sg = (v > 0.f) ? 1.f : ((v < 0.f) ? -1.f : 0.f);
            ws[((t * 2 + p) * 64 + l) * 8 + j] = (_Float16)(s * sg);
        }
    }
}

// ---- kernel 2: the conv ---------------------------------------------------
__global__ __launch_bounds__(320) void bnn_conv3d_dma(
        const float* __restrict__ x, const _Float16* __restrict__ ws,
        float* __restrict__ out) {
    extern __shared__ __align__(16) char lds[];

    const int tid  = threadIdx.x;
    const int lane = tid & 63;
    const int wv   = tid >> 6;         // 0..4

    const int bid = blockIdx.x;        // 512 = 8n * 16d * 4 h-chunks
    const int hc  = bid & 3;
    const int d   = (bid >> 2) & 15;
    const int n   = bid >> 6;
    const int h0  = hc * 40;           // output rows h0..h0+39; input h0-1..h0+40

    // ---- DMA source bases: instr q covers ch-octet q, w in [32wv,32wv+32) --
    // lane: ch = q*8 + (lane>>3), w = 32wv + (lane&7)*4 (float4)
    const float* qb[4];
    {
        const int chl = lane >> 3;
        const int wl  = (lane & 7) * 4;
        #pragma unroll
        for (int q = 0; q < 4; ++q)
            qb[q] = x + (size_t)(n * 32 + q * 8 + chl) * DHW + d * HW + wv * 32 + wl;
    }

    // ---- weight fragments first (so vmcnt(0) drain doesn't touch DMA) -----
    half8 wf0[9], wf1[9];
    {
        const half8* fb = (const half8*)ws;
        #pragma unroll
        for (int t = 0; t < 9; ++t) {
            wf0[t] = fb[(t * 2 + 0) * 64 + lane];
            wf1[t] = fb[(t * 2 + 1) * 64 + lane];
        }
    }
    asm volatile("s_waitcnt vmcnt(0)" ::: "memory");
    __builtin_amdgcn_sched_barrier(0);

    // ---- ring halo cells (w1x = 0,161) zeroed once -------------------------
    if (tid < 128) {
        const int slot = tid >> 5, w1x = ((tid >> 4) & 1) ? 161 : 0, word = tid & 15;
        *(uint32_t*)(lds + slot * RING_SLOT_B + w1x * 64 + word * 4) = 0u;
    }

    // ---- PACK precompute: lane handles ring cell pcell, 16 channels -------
    // wave wv packs exactly the cells its own DMA staged (w in [32wv,32wv+32))
    const int pcell = 32 * wv + 1 + (lane >> 1);     // w1x (swizzled cell id)
    const int w1p   = w1s(pcell);                    // logical w1 (involution)
    const int wloc  = (w1p - 1) - wv * 32;           // 0..31 within wave panel
    const int chb   = (lane & 1) * 16;
    int soff[16];                                    // scratch byte offsets
    #pragma unroll
    for (int c = 0; c < 16; ++c) {
        const int ch = chb + c;
        soff[c] = (wv * 4 + (ch >> 3)) * 1024 + ((ch & 7) * 8 + (wloc >> 2)) * 16
                + (wloc & 3) * 4;
    }
    const int f2p = f2v(pcell);
    const int rb0 = pcell * 64 + ((((lane & 1) * 2)     ^ f2p) * 16);
    const int rb1 = pcell * 64 + ((((lane & 1) * 2 + 1) ^ f2p) * 16);

    // ---- COMPUTE precompute (R5-verified fragment path) --------------------
    const int s16 = lane & 15, kgr = lane >> 4;
    int rdo[2][3];
    #pragma unroll
    for (int gi = 0; gi < 2; ++gi)
        #pragma unroll
        for (int kw = 0; kw < 3; ++kw) {
            const int w1 = (2 * wv + gi) * 16 + s16 + kw;
            rdo[gi][kw] = (w1s(w1) * 32 + ((kgr ^ f2v(w1)) * 8)) * 2;  // bytes
        }
    float* ob = out + (size_t)(n * 32 + s16) * DHW + d * HW + wv * 32 + kgr * 4;

    auto DMA = [&](int r) {            // 4 instrs/wave; clamped h (garbage OK)
        int h = h0 - 1 + r; h = h < 0 ? 0 : (h > 159 ? 159 : h);
        char* dst = lds + RING_B + (r % 3) * SCR_SLOT_B + wv * 4096;
        #pragma unroll
        for (int q = 0; q < 4; ++q)
            gld16(qb[q] + h * 160, dst + q * 1024);
        __builtin_amdgcn_sched_barrier(0);   // pin issue before compute
    };
    auto PACK = [&](int r) {           // scratch f32 -> f16 ring (own-wave)
        const int hr = h0 - 1 + r;
        const char* sl = lds + RING_B + (r % 3) * SCR_SLOT_B;
        char* rg = lds + (r & 3) * RING_SLOT_B;
        half8 o0 = {}, o1 = {};
        if (hr >= 0 && hr < 160) {     // block-uniform
            float f[16];
            #pragma unroll
            for (int c = 0; c < 16; ++c) f[c] = *(const float*)(sl + soff[c]);
            #pragma unroll
            for (int c = 0; c < 8; ++c) { o0[c] = (_Float16)f[c]; o1[c] = (_Float16)f[c + 8]; }
        }
        *(half8*)(rg + rb0) = o0;
        *(half8*)(rg + rb1) = o1;
    };
    auto COMPUTE = [&](int t) {        // output row h0+t; reads ring t,t+1,t+2
        #pragma unroll
        for (int gi = 0; gi < 2; ++gi) {
            floatx4 a0 = {0.f, 0.f, 0.f, 0.f};
            floatx4 a1 = {0.f, 0.f, 0.f, 0.f};
            #pragma unroll
            for (int kh = 0; kh < 3; ++kh) {
                const char* sb = lds + ((t + kh) & 3) * RING_SLOT_B;
                #pragma unroll
                for (int kw = 0; kw < 3; ++kw) {
                    const half8 a = *(const half8*)(sb + rdo[gi][kw]);
                    const int tp = kh * 3 + kw;
                    a0 = __builtin_amdgcn_mfma_f32_16x16x32_f16(a, wf0[tp], a0, 0, 0, 0);
                    a1 = __builtin_amdgcn_mfma_f32_16x16x32_f16(a, wf1[tp], a1, 0, 0, 0);
                }
            }
            float* op = ob + (size_t)(h0 + t) * 160 + gi * 16;
            *(floatx4*)op = a0;                       // o 0..15
            *(floatx4*)(op + (size_t)16 * DHW) = a1;  // o 16..31
        }
    };

    // ---------------- pipeline ----------------
    // vmcnt audit (per wave, I=4 DMA + S=4 stores per row, in-order retire):
    DMA(0); DMA(1); DMA(2);
    VMCNT(8);  PACK(0);                // rows 1,2 in flight
    VMCNT(4);  PACK(1);                // row 2 in flight
    barrier_raw();
    DMA(3);
    // t=0: outstanding = DMA(3)
    VMCNT(4);  PACK(2); barrier_raw(); DMA(4); COMPUTE(0);
    // t=1: outstanding = DMA(4) + stores(0)
    VMCNT(8);  PACK(3); barrier_raw(); DMA(5); COMPUTE(1);
    // steady: younger than DMA(t+2) = stores(t-2) + DMA(t+3) + stores(t-1)
    for (int t = 2; t <= 37; ++t) {
        VMCNT(12); PACK(t + 2); barrier_raw(); DMA(t + 4); COMPUTE(t);
    }
    // t=38: younger than DMA(40) = stores(36) + DMA(41) + stores(37)
    VMCNT(12); PACK(40); barrier_raw(); COMPUTE(38);
    // t=39: younger than DMA(41) = stores(37) + stores(38)
    VMCNT(8);  PACK(41); barrier_raw(); COMPUTE(39);
}

extern "C" void kernel_launch(void* const* d_in, const int* in_sizes, int n_in,
                              void* d_out, int out_size, void* d_ws, size_t ws_size,
                              hipStream_t stream) {
    const float* x = (const float*)d_in[0];
    const float* w = (const float*)d_in[1];
    float* out = (float*)d_out;
    _Float16* ws = (_Float16*)d_ws;     // 9216 halfs = 18 KB scratch
    bnn_wprep_kernel<<<dim3(1), dim3(256), 0, stream>>>(w, ws);
    (void)hipFuncSetAttribute((const void*)&bnn_conv3d_dma,
                              hipFuncAttributeMaxDynamicSharedMemorySize, LDS_TOTAL);
    // grid: 8 n * 16 d * 4 h-chunks of 40 rows (1 block/CU, 2 passes)
    bnn_conv3d_dma<<<dim3(512), dim3(320), LDS_TOTAL, stream>>>(x, ws, out);
}